// Round 12
// baseline (188.425 us; speedup 1.0000x reference)
//
#include <hip/hip_runtime.h>
#include <math.h>

#define NHEAD  16
#define DHEAD  64
#define DLAT   32
#define TSEQ   2048
#define NBATCH 2
#define CDIM   1024
#define MROWS  (NBATCH*TSEQ)   // 4096

typedef __attribute__((ext_vector_type(8))) short bf16x8;
typedef __attribute__((ext_vector_type(4))) short bf16x4;
typedef __attribute__((ext_vector_type(4))) float f32x4;

#define AS1 __attribute__((address_space(1)))
#define AS3 __attribute__((address_space(3)))

__device__ __forceinline__ unsigned short f2bf(float f) {
    union { float f; unsigned u; } v; v.f = f;
    unsigned r = v.u + 0x7fff + ((v.u >> 16) & 1);   // RNE
    return (unsigned short)(r >> 16);
}

// pack two floats -> bf16 pair (RNE), lo | hi<<16
__device__ __forceinline__ unsigned pk2(float lo, float hi) {
    return (unsigned)f2bf(lo) | ((unsigned)f2bf(hi) << 16);
}

// pack bf16(lo)|bf16(hi)<<16 by truncation — one v_perm_b32
__device__ __forceinline__ unsigned pack_trunc(float hi, float lo) {
    return __builtin_amdgcn_perm(__float_as_uint(hi), __float_as_uint(lo), 0x07060302u);
}

__device__ __forceinline__ void gld_lds16(const unsigned short* g, unsigned short* l) {
    __builtin_amdgcn_global_load_lds((const AS1 void*)g, (AS3 void*)l, 16, 0, 0);
}

// 16x16x16 bf16 MFMA: builtin if present, else raw instruction (gfx950 has it)
__device__ __forceinline__ f32x4 mfma_16x16x16_bf16(bf16x4 a, bf16x4 b, f32x4 c) {
#if __has_builtin(__builtin_amdgcn_mfma_f32_16x16x16bf16_1k)
    return __builtin_amdgcn_mfma_f32_16x16x16bf16_1k(a, b, c, 0, 0, 0);
#else
    asm volatile("v_mfma_f32_16x16x16_bf16 %0, %1, %2, %0\n\ts_nop 4"
                 : "+v"(c) : "v"(a), "v"(b));
    return c;
#endif
}

#define QSCALE 0.18033688011112042f   // 0.125 * log2(e)
#define RFREQ  0.28782313662425572f   // ln(10000)/32

// ---------------- fp32 -> bf16: x and all six weights in ONE launch ----------------
__global__ __launch_bounds__(256) void cvt_all(
        const float* __restrict__ x,  const float* __restrict__ wq,
        const float* __restrict__ wk, const float* __restrict__ wv,
        const float* __restrict__ wc, const float* __restrict__ wku,
        const float* __restrict__ wvu,
        unsigned short* __restrict__ xb, unsigned short* __restrict__ wall) {
    int i = (blockIdx.x * 256 + threadIdx.x) * 4;
    const float* src; unsigned short* dst; int off;
    if      (i < 4194304) { src = x;   dst = xb;             off = 0;       }
    else if (i < 5242880) { src = wq;  dst = wall;           off = 4194304; }
    else if (i < 5767168) { src = wk;  dst = wall + 1048576; off = 5242880; }
    else if (i < 6291456) { src = wv;  dst = wall + 1572864; off = 5767168; }
    else if (i < 7340032) { src = wc;  dst = wall + 2097152; off = 6291456; }
    else if (i < 7342080) { src = wku; dst = wall + 3145728; off = 7340032; }
    else                  { src = wvu; dst = wall + 3147776; off = 7342080; }
    float4 v = *(const float4*)(src + (i - off));
    ushort4 o = { f2bf(v.x), f2bf(v.y), f2bf(v.z), f2bf(v.w) };
    *(ushort4*)(dst + (i - off)) = o;
}

// ---------------- MFMA GEMM core: 128x64 tile, BK=64, 8 waves, XOR-swizzled LDS ----------------
// R17 (kept): [.][64] tiles + flash's swizzle (2-way = free), BK=64 halves barriers.
__device__ __forceinline__ void gemm_core(
        const unsigned short* __restrict__ A, const unsigned short* __restrict__ W,
        int K, int bm, int bn, unsigned short* As, unsigned short* Bs,
        f32x4 (&acc)[2][2]) {
    const int tid = threadIdx.x;
    const int w = tid >> 6, lane = tid & 63;
    const int quad = lane >> 4, l16 = lane & 15;
    const int wm = (w >> 1) * 32, wn = (w & 1) * 32;

    // staging lane-mapping: row = +(lane>>3), phys colblk = lane&7,
    // logical colblk = phys ^ (row&7)
    const int r8 = lane >> 3, c8 = lane & 7;
    const int scl = (c8 ^ r8) * 8;

    const unsigned short* Ag0 = A + (size_t)(bm +      w*8 + r8) * K + scl;
    const unsigned short* Ag1 = A + (size_t)(bm + 64 + w*8 + r8) * K + scl;
    const unsigned short* Wg0 = W + (size_t)(bn +      w*8 + r8) * K + scl;
    unsigned short* AsD0 = &As[(     w*8) * 64];
    unsigned short* AsD1 = &As[(64 + w*8) * 64];
    unsigned short* BsD  = &Bs[(     w*8) * 64];

    // swizzled fragment-read offsets
    const int fx0 = (quad ^ (l16 & 7)) * 8;
    const int fx1 = ((quad + 4) ^ (l16 & 7)) * 8;

    for (int k0 = 0; k0 < K; k0 += 64) {
        gld_lds16(Ag0 + k0, AsD0);
        gld_lds16(Ag1 + k0, AsD1);
        gld_lds16(Wg0 + k0, BsD);
        __syncthreads();
        bf16x8 af0[2], af1[2], bf0[2], bf1[2];
        #pragma unroll
        for (int t = 0; t < 2; ++t) {
            af0[t] = *(const bf16x8*)&As[(wm + t*16 + l16)*64 + fx0];
            af1[t] = *(const bf16x8*)&As[(wm + t*16 + l16)*64 + fx1];
        }
        #pragma unroll
        for (int c = 0; c < 2; ++c) {
            bf0[c] = *(const bf16x8*)&Bs[(wn + c*16 + l16)*64 + fx0];
            bf1[c] = *(const bf16x8*)&Bs[(wn + c*16 + l16)*64 + fx1];
        }
        #pragma unroll
        for (int t = 0; t < 2; ++t)
            #pragma unroll
            for (int c = 0; c < 2; ++c) {
                acc[t][c] = __builtin_amdgcn_mfma_f32_16x16x32_bf16(af0[t], bf0[c], acc[t][c], 0, 0, 0);
                acc[t][c] = __builtin_amdgcn_mfma_f32_16x16x32_bf16(af1[t], bf1[c], acc[t][c], 0, 0, 0);
            }
        __syncthreads();
    }
}

// ---------------- gemm_proj with fused q-RoPE epilogue ----------------
// R18: q blocks (bn<1024, exactly one head each since DHEAD=64) RoPE in-register
// and write bf16 qb DIRECTLY — the fp32 qproj 16MB write + 16MB read round-trip
// and latup's q path are deleted. Pair (d, d^1) lives in lanes (l16, l16^1):
// partner via shfl_xor(x,1); own-dim angle freq = (d&31) = c*16+l16 (wn drops
// out); 16 sincos/thread, once per block. Precision path identical to latup's
// (fp32 acc -> fp32 RoPE -> RNE bf16). kl/vl blocks unchanged (fp32 outputs).
__global__ __launch_bounds__(512, 4) void gemm_proj(
        const unsigned short* __restrict__ A, const unsigned short* __restrict__ W,
        unsigned short* __restrict__ qbo, float* __restrict__ okl,
        float* __restrict__ ovl, int K) {
    __shared__ unsigned short As[128*64];   // 16 KB
    __shared__ unsigned short Bs[64*64];    // 8 KB
    const int bm = blockIdx.y * 128, bn = blockIdx.x * 64;
    f32x4 acc[2][2] = {};
    gemm_core(A, W, K, bm, bn, As, Bs, acc);

    const int tid = threadIdx.x;
    const int w = tid >> 6, lane = tid & 63;
    const int quad = lane >> 4, l16 = lane & 15;
    const int wm = (w >> 1) * 32, wn = (w & 1) * 32;

    if (bn < 1024) {
        // fused RoPE -> qb (bf16)
        const int h = bn >> 6;
        const int p = l16 & 1;
        const float invf0 = __expf(-(float)(l16)      * RFREQ);   // c=0: freq idx l16
        const float invf1 = __expf(-(float)(16 + l16) * RFREQ);   // c=1: freq idx 16+l16
        #pragma unroll
        for (int t = 0; t < 2; ++t)
            #pragma unroll
            for (int r = 0; r < 4; ++r) {
                int row = bm + wm + t*16 + quad*4 + r;   // global token row 0..4095
                int ts  = row & 2047;
                float tf = (float)ts;
                size_t obase = (((size_t)((row >> 11)*16 + h))*TSEQ + ts)*DHEAD;
                #pragma unroll
                for (int c = 0; c < 2; ++c) {
                    float x  = acc[t][c][r];
                    float px = __shfl_xor(x, 1, 64);
                    float sv, cv;
                    __sincosf(tf * (c ? invf1 : invf0), &sv, &cv);
                    float o = (x*cv + (p ? px : -px)*sv) * QSCALE;
                    float po = __shfl_xor(o, 1, 64);
                    if (!p) {
                        unsigned pr = pk2(o, po);
                        *(unsigned*)&qbo[obase + wn + c*16 + l16] = pr;
                    }
                }
            }
    } else {
        float* base; int ldo;
        if (bn < 1536) { base = okl + (bn - 1024); ldo = 512; }
        else           { base = ovl + (bn - 1536); ldo = 512; }
        #pragma unroll
        for (int t = 0; t < 2; ++t)
            #pragma unroll
            for (int c = 0; c < 2; ++c)
                #pragma unroll
                for (int r = 0; r < 4; ++r) {
                    int row = bm + wm + t*16 + quad*4 + r;
                    int col = wn + c*16 + l16;
                    base[(size_t)row * ldo + col] = acc[t][c][r];
                }
    }
}

__global__ __launch_bounds__(512, 4) void gemm_out(
        const unsigned short* __restrict__ A, const unsigned short* __restrict__ W,
        float* __restrict__ O, int N, int K) {
    __shared__ unsigned short As[128*64];   // 16 KB
    __shared__ unsigned short Bs[64*64];    // 8 KB
    const int bm = blockIdx.y * 128, bn = blockIdx.x * 64;
    f32x4 acc[2][2] = {};
    gemm_core(A, W, K, bm, bn, As, Bs, acc);

    const int tid = threadIdx.x;
    const int w = tid >> 6, lane = tid & 63;
    const int quad = lane >> 4, l16 = lane & 15;
    const int wm = (w >> 1) * 32, wn = (w & 1) * 32;
    #pragma unroll
    for (int t = 0; t < 2; ++t)
        #pragma unroll
        for (int c = 0; c < 2; ++c)
            #pragma unroll
            for (int r = 0; r < 4; ++r) {
                int row = bm + wm + t*16 + quad*4 + r;
                int col = bn + wn + c*16 + l16;
                O[(size_t)row * N + col] = acc[t][c][r];
            }
}

// ---------------- latent up-proj (k,v only) via MFMA + RoPE ----------------
// R18: q path removed (fused into gemm_proj). k/v paths byte-identical to R11.
__global__ __launch_bounds__(256) void latup(
        const float* __restrict__ klat, const float* __restrict__ vlat,
        const unsigned short* __restrict__ wkub, const unsigned short* __restrict__ wvub,
        unsigned short* __restrict__ kb, unsigned short* __restrict__ vt) {
    __shared__ __attribute__((aligned(16))) unsigned short ksh[4][16][72];
    __shared__ __attribute__((aligned(16))) unsigned short vsh[4][64][24];

    const int bh = blockIdx.y, b = bh >> 4, h = bh & 15;
    const int tid = threadIdx.x, w = tid >> 6, lane = tid & 63;
    const int quad = lane >> 4, l16 = lane & 15;
    const int tw = blockIdx.x * 64 + w * 16;   // wave's 16-token base
    const int t  = tw + l16;

    // B-frags (latents): row = token(l16), k = quad*8..+7 — 128 B/token across 4 lanes
    const float* klp = klat + ((size_t)(b*TSEQ + t))*(NHEAD*DLAT) + h*DLAT + quad*8;
    const float* vlp = vlat + ((size_t)(b*TSEQ + t))*(NHEAD*DLAT) + h*DLAT + quad*8;
    float4 kA = *(const float4*)klp, kB = *(const float4*)(klp + 4);
    float4 vA = *(const float4*)vlp, vB = *(const float4*)(vlp + 4);

    // A-frags (Wku/Wvu bf16): row = dim(c*16+l16), k = quad*8..+7
    bf16x8 xk[4], xv[4];
    #pragma unroll
    for (int c = 0; c < 4; ++c) {
        xk[c] = *(const bf16x8*)&wkub[(c*16 + l16)*DLAT + quad*8];
        xv[c] = *(const bf16x8*)&wvub[(c*16 + l16)*DLAT + quad*8];
    }

    union { bf16x8 v; unsigned u[4]; } yk, yv;
    yk.u[0] = pk2(kA.x, kA.y); yk.u[1] = pk2(kA.z, kA.w);
    yk.u[2] = pk2(kB.x, kB.y); yk.u[3] = pk2(kB.z, kB.w);
    yv.u[0] = pk2(vA.x, vA.y); yv.u[1] = pk2(vA.z, vA.w);
    yv.u[2] = pk2(vB.x, vB.y); yv.u[3] = pk2(vB.z, vB.w);

    f32x4 aK[4], aV[4];
    #pragma unroll
    for (int c = 0; c < 4; ++c) {
        f32x4 z = {0.f, 0.f, 0.f, 0.f};
        aK[c] = __builtin_amdgcn_mfma_f32_16x16x32_bf16(xk[c], yk.v, z, 0, 0, 0);
        aV[c] = __builtin_amdgcn_mfma_f32_16x16x32_bf16(xv[c], yv.v, z, 0, 0, 0);
    }

    // angles: dim d = (c&1)*16 + quad*4 + j, freq idx = d&31 — only 8 distinct/thread
    float C0[4], S0[4], C1[4], S1[4];
    const float tf = (float)t;
    #pragma unroll
    for (int j = 0; j < 4; ++j) {
        float f0 = (float)(quad*4 + j);
        __sincosf(tf * __expf(-f0 * RFREQ),          &S0[j], &C0[j]);
        __sincosf(tf * __expf(-(f0 + 16.f) * RFREQ), &S1[j], &C1[j]);
    }

    #pragma unroll
    for (int c = 0; c < 4; ++c) {
        const float* Cs = (c & 1) ? C1 : C0;
        const float* Ss = (c & 1) ? S1 : S0;
        float a0 = aK[c][0], a1 = aK[c][1], a2 = aK[c][2], a3 = aK[c][3];
        unsigned kw0 = pk2(a0*Cs[0] - a1*Ss[0], a1*Cs[1] + a0*Ss[1]);
        unsigned kw1 = pk2(a2*Cs[2] - a3*Ss[2], a3*Cs[3] + a2*Ss[3]);
        *(uint2*)&ksh[w][l16][c*16 + quad*4] = make_uint2(kw0, kw1);

        vsh[w][c*16 + quad*4 + 0][l16] = f2bf(aV[c][0]);
        vsh[w][c*16 + quad*4 + 1][l16] = f2bf(aV[c][1]);
        vsh[w][c*16 + quad*4 + 2][l16] = f2bf(aV[c][2]);
        vsh[w][c*16 + quad*4 + 3][l16] = f2bf(aV[c][3]);
    }

    // wave-local transpose: lockstep + drain LDS writes (no __syncthreads needed)
    __asm__ __volatile__("s_waitcnt lgkmcnt(0)" ::: "memory");

    const int ro = lane >> 2, co = (lane & 3) * 16;
    size_t go = ((size_t)bh*TSEQ + tw + ro)*DHEAD + co;
    int4 k0o = *(const int4*)&ksh[w][ro][co];
    int4 k1o = *(const int4*)&ksh[w][ro][co + 8];
    *(int4*)&kb[go]     = k0o;
    *(int4*)&kb[go + 8] = k1o;

    size_t vo = ((size_t)bh*DHEAD + lane)*TSEQ + tw;
    int4 v0o = *(const int4*)&vsh[w][lane][0];
    int4 v1o = *(const int4*)&vsh[w][lane][8];
    *(int4*)&vt[vo]     = v0o;
    *(int4*)&vt[vo + 8] = v1o;
}

// ---------------- Flash attention: 8-wave blocks, wave-split qt pair (R10, 49.7us) ----------------
// Frozen — best-measured structure (Occ 35%, VALU 53% + MFMA 22% = 75%). Do not touch.
__device__ __forceinline__ void online_sm(f32x4 (&s)[8], float& m_run, float& l_run,
                                          f32x4 (&o)[4]) {
    float mx = -1e30f;
    #pragma unroll
    for (int c = 0; c < 8; ++c)
        #pragma unroll
        for (int r = 0; r < 4; ++r) mx = fmaxf(mx, s[c][r]);
    mx = fmaxf(mx, __shfl_xor(mx, 16, 64));
    mx = fmaxf(mx, __shfl_xor(mx, 32, 64));
    if (!__all(mx <= m_run + 8.f)) {   // defer-max: P bounded by 2^8
        float mn = fmaxf(m_run, mx);
        float alpha = __builtin_exp2f(m_run - mn);
        m_run = mn;
        l_run *= alpha;
        #pragma unroll
        for (int c = 0; c < 4; ++c)
            #pragma unroll
            for (int r = 0; r < 4; ++r) o[c][r] *= alpha;
    }
    float ls = 0.f;
    #pragma unroll
    for (int c = 0; c < 8; ++c)
        #pragma unroll
        for (int r = 0; r < 4; ++r) {
            float p = __builtin_exp2f(s[c][r] - m_run);
            s[c][r] = p;
            ls += p;
        }
    ls += __shfl_xor(ls, 16, 64);
    ls += __shfl_xor(ls, 32, 64);
    l_run += ls;
}

__global__ __launch_bounds__(512, 4) void flash_attn(
        const unsigned short* __restrict__ qb, const unsigned short* __restrict__ kb,
        const unsigned short* __restrict__ vtb, unsigned short* __restrict__ yatt) {
    const int bh = blockIdx.x;
    const int b = bh >> 4, h = bh & 15;

    __shared__ unsigned short Ks[2][128][64];    // 32 KB
    __shared__ unsigned short VTs[2][64][128];   // 32 KB

    const int tid  = threadIdx.x;
    const int w    = tid >> 6;          // 0..7
    const int lane = tid & 63;
    const int quad = lane >> 4;
    const int l16  = lane & 15;
    const bool heavy = (w >= 4);
    const int wq = w & 3;               // 16-row group within this wave's half

    const int qtA = blockIdx.y;          // 0..15 (light half)
    const int qtB = 31 - qtA;            // 16..31 (heavy half)
    const int qt  = heavy ? qtB : qtA;
    const int myN = (qt + 2) >> 1;       // KV 128-tiles this wave computes
    const int nB  = (qtB + 2) >> 1;      // loop bound (heavy side)

    const unsigned short* Kbase = kb  + (size_t)bh * TSEQ * DHEAD;
    const unsigned short* Vbase = vtb + (size_t)bh * DHEAD * TSEQ;

    // K DMA: wave w stages tile rows [w*16, w*16+16) — 2 issues x 8 rows
    const int kr8 = lane >> 3, kc8 = lane & 7;
    const int kcl = (kc8 ^ kr8) * 8;            // phys colblk = log ^ (row&7)
    // V DMA: wave w stages dim rows [w*8, w*8+8) — 2 issues x 4 rows
    const int vr4 = lane >> 4, vcp = lane & 15; // phys colblk = log ^ (row&15)

    // swizzled MFMA read offsets
    const int kx0 = (quad ^ (l16 & 7)) * 8;
    const int kx1 = ((quad + 4) ^ (l16 & 7)) * 8;
    const int vq = (quad >> 1), vodd = (quad & 1) * 4;

    const unsigned short* qbase =
        qb + ((size_t)bh*TSEQ + qt*64 + wq*16 + l16) * DHEAD + quad*8;
    bf16x8 q0 = *(const bf16x8*)qbase;
    bf16x8 q1 = *(const bf16x8*)(qbase + 32);

    f32x4 oacc[4] = {};
    float m_run = -1e30f, l_run = 0.f;

    #pragma unroll
    for (int i = 0; i < 2; ++i) {   // preload tile 0 into buf 0
        gld_lds16(Kbase + (size_t)(w*16 + i*8 + kr8)*DHEAD + kcl,
                  &Ks[0][w*16 + i*8][0]);
        int vrow = w*8 + i*4 + vr4;
        int vcl = (vcp ^ (vrow & 15)) * 8;
        gld_lds16(Vbase + (size_t)vrow*TSEQ + vcl, &VTs[0][w*8 + i*4][0]);
    }
    __syncthreads();

    for (int j = 0; j < nB; ++j) {
        const int buf = j & 1;
        if (j + 1 < nB) {   // async DMA prefetch of next tile into buf^1 (ALL waves)
            const int kc = (j + 1) * 128;
            #pragma unroll
            for (int i = 0; i < 2; ++i) {
                gld_lds16(Kbase + (size_t)(kc + w*16 + i*8 + kr8)*DHEAD + kcl,
                          &Ks[buf^1][w*16 + i*8][0]);
                int vrow = w*8 + i*4 + vr4;
                int vcl = (vcp ^ (vrow & 15)) * 8;
                gld_lds16(Vbase + (size_t)vrow*TSEQ + kc + vcl,
                          &VTs[buf^1][w*8 + i*4][0]);
            }
        }

        if (j < myN) {   // wave-uniform guard: light waves idle after their range
            // S^T = K Q^T (8 chunks of 16 K-rows), log2 units
            f32x4 s[8];
            __builtin_amdgcn_s_setprio(1);
            #pragma unroll
            for (int c = 0; c < 8; ++c) {
                bf16x8 ak0 = *(const bf16x8*)&Ks[buf][c*16 + l16][kx0];
                bf16x8 ak1 = *(const bf16x8*)&Ks[buf][c*16 + l16][kx1];
                f32x4 z = {0.f, 0.f, 0.f, 0.f};
                z = __builtin_amdgcn_mfma_f32_16x16x32_bf16(ak0, q0, z, 0, 0, 0);
                z = __builtin_amdgcn_mfma_f32_16x16x32_bf16(ak1, q1, z, 0, 0, 0);
                s[c] = z;
            }
            __builtin_amdgcn_s_setprio(0);

            if (j == myN - 1) {   // causal mask (covers the 128-overhang too)
                #pragma unroll
                for (int c = 0; c < 8; ++c)
                    #pragma unroll
                    for (int r = 0; r < 4; ++r)
                        if (j*128 + c*16 + quad*4 + r > qt*64 + wq*16 + l16)
                            s[c][r] = -1e30f;
            }

            online_sm(s, m_run, l_run, oacc);

            // PV: B-frag = packed P (k=quad*4+e matches 16x16x16), A = swizzled V^T
            __builtin_amdgcn_s_setprio(1);
            #pragma unroll
            for (int c = 0; c < 8; ++c) {
                union { bf16x4 v; unsigned u[2]; } bP;
                bP.u[0] = pack_trunc(s[c][1], s[c][0]);
                bP.u[1] = pack_trunc(s[c][3], s[c][2]);
                const int vcol = ((2*c + vq) ^ l16) * 8 + vodd;
                #pragma unroll
                for (int dc = 0; dc < 4; ++dc) {
                    bf16x4 av = *(const bf16x4*)&VTs[buf][dc*16 + l16][vcol];
                    oacc[dc] = mfma_16x16x16_bf16(av, bP.v, oacc[dc]);
                }
            }
            __builtin_amdgcn_s_setprio(0);
        }

        __syncthreads();   // drains prefetch DMA + protects buf reuse (all waves)
    }

    // epilogue: O^T -> O via per-wave LDS slab (stride 72), coalesced 16B stores
    float invl = 1.0f / l_run;
    unsigned short* Wt = &Ks[0][0][0] + w * (16*72);   // 8 slabs x 2304B < 32KB
    #pragma unroll
    for (int c = 0; c < 4; ++c)
        #pragma unroll
        for (int r = 0; r < 4; ++r)
            Wt[(size_t)l16*72 + c*16 + quad*4 + r] = f2bf(oacc[c][r] * invl);
    __asm__ __volatile__("" ::: "memory");
    #pragma unroll
    for (int p = 0; p < 2; ++p) {
        int row = p*8 + (lane >> 3);
        int d0 = (lane & 7) * 8;
        int4 val = *(const int4*)&Wt[row*72 + d0];
        int tg = qt*64 + wq*16 + row;
        *(int4*)&yatt[((size_t)(b*TSEQ + tg))*CDIM + h*DHEAD + d0] = val;
    }
}

extern "C" void kernel_launch(void* const* d_in, const int* in_sizes, int n_in,
                              void* d_out, int out_size, void* d_ws, size_t ws_size,
                              hipStream_t stream) {
    const float* x   = (const float*)d_in[0];
    const float* Wq  = (const float*)d_in[1];
    const float* Wk  = (const float*)d_in[2];
    const float* Wv  = (const float*)d_in[3];
    const float* Wku = (const float*)d_in[4];
    const float* Wvu = (const float*)d_in[5];
    const float* Wc  = (const float*)d_in[6];

    float* out_y  = (float*)d_out;
    float* out_kl = out_y  + (size_t)MROWS * CDIM;
    float* out_vl = out_kl + (size_t)MROWS * NHEAD*DLAT;

    float* qproj = (float*)d_ws;                                           // 16 MB (yatt alias only)
    unsigned short* xb   = (unsigned short*)(qproj + (size_t)MROWS*CDIM);  // 8 MB
    unsigned short* qb   = xb  + (size_t)MROWS*CDIM;                       // 8 MB
    unsigned short* kb   = qb  + (size_t)MROWS*CDIM;                       // 8 MB
    unsigned short* vt   = kb  + (size_t)MROWS*CDIM;                       // 8 MB
    unsigned short* wall = vt  + (size_t)MROWS*CDIM;                       // [Wq;Wk;Wv;Wc;Wku;Wvu]
    unsigned short* wcb  = wall + (size_t)2048*CDIM;
    unsigned short* wkub = wall + 3145728;
    unsigned short* wvub = wall + 3147776;
    unsigned short* yatt = (unsigned short*)qproj;   // qproj itself is dead (q fused)

    cvt_all<<<7172, 256, 0, stream>>>(x, Wq, Wk, Wv, Wc, Wku, Wvu, xb, wall);

    gemm_proj<<<dim3(2048/64, MROWS/128), 512, 0, stream>>>(
        xb, wall, qb, out_kl, out_vl, CDIM);

    latup<<<dim3(TSEQ/64, NBATCH*NHEAD), 256, 0, stream>>>(
        out_kl, out_vl, wkub, wvub, kb, vt);

    flash_attn<<<dim3(NBATCH*NHEAD, 16), 512, 0, stream>>>(qb, kb, vt, yatt);

    gemm_out<<<dim3(CDIM/64, MROWS/128), 512, 0, stream>>>(yatt, wcb, out_y, CDIM, CDIM);
}

// Round 13
// 182.226 us; speedup vs baseline: 1.0340x; 1.0340x over previous
//
#include <hip/hip_runtime.h>
#include <math.h>

#define NHEAD  16
#define DHEAD  64
#define DLAT   32
#define TSEQ   2048
#define NBATCH 2
#define CDIM   1024
#define MROWS  (NBATCH*TSEQ)   // 4096

typedef __attribute__((ext_vector_type(8))) short bf16x8;
typedef __attribute__((ext_vector_type(4))) short bf16x4;
typedef __attribute__((ext_vector_type(4))) float f32x4;

#define AS1 __attribute__((address_space(1)))
#define AS3 __attribute__((address_space(3)))

__device__ __forceinline__ unsigned short f2bf(float f) {
    union { float f; unsigned u; } v; v.f = f;
    unsigned r = v.u + 0x7fff + ((v.u >> 16) & 1);   // RNE
    return (unsigned short)(r >> 16);
}

// pack two floats -> bf16 pair (RNE), lo | hi<<16
__device__ __forceinline__ unsigned pk2(float lo, float hi) {
    return (unsigned)f2bf(lo) | ((unsigned)f2bf(hi) << 16);
}

// pack bf16(lo)|bf16(hi)<<16 by truncation — one v_perm_b32
__device__ __forceinline__ unsigned pack_trunc(float hi, float lo) {
    return __builtin_amdgcn_perm(__float_as_uint(hi), __float_as_uint(lo), 0x07060302u);
}

__device__ __forceinline__ void gld_lds16(const unsigned short* g, unsigned short* l) {
    __builtin_amdgcn_global_load_lds((const AS1 void*)g, (AS3 void*)l, 16, 0, 0);
}

// 16x16x16 bf16 MFMA: builtin if present, else raw instruction (gfx950 has it)
__device__ __forceinline__ f32x4 mfma_16x16x16_bf16(bf16x4 a, bf16x4 b, f32x4 c) {
#if __has_builtin(__builtin_amdgcn_mfma_f32_16x16x16bf16_1k)
    return __builtin_amdgcn_mfma_f32_16x16x16bf16_1k(a, b, c, 0, 0, 0);
#else
    asm volatile("v_mfma_f32_16x16x16_bf16 %0, %1, %2, %0\n\ts_nop 4"
                 : "+v"(c) : "v"(a), "v"(b));
    return c;
#endif
}

#define QSCALE 0.18033688011112042f   // 0.125 * log2(e)
#define RFREQ  0.28782313662425572f   // ln(10000)/32

// ---------------- fp32 -> bf16: x and all six weights in ONE launch ----------------
__global__ __launch_bounds__(256) void cvt_all(
        const float* __restrict__ x,  const float* __restrict__ wq,
        const float* __restrict__ wk, const float* __restrict__ wv,
        const float* __restrict__ wc, const float* __restrict__ wku,
        const float* __restrict__ wvu,
        unsigned short* __restrict__ xb, unsigned short* __restrict__ wall) {
    int i = (blockIdx.x * 256 + threadIdx.x) * 4;
    const float* src; unsigned short* dst; int off;
    if      (i < 4194304) { src = x;   dst = xb;             off = 0;       }
    else if (i < 5242880) { src = wq;  dst = wall;           off = 4194304; }
    else if (i < 5767168) { src = wk;  dst = wall + 1048576; off = 5242880; }
    else if (i < 6291456) { src = wv;  dst = wall + 1572864; off = 5767168; }
    else if (i < 7340032) { src = wc;  dst = wall + 2097152; off = 6291456; }
    else if (i < 7342080) { src = wku; dst = wall + 3145728; off = 7340032; }
    else                  { src = wvu; dst = wall + 3147776; off = 7342080; }
    float4 v = *(const float4*)(src + (i - off));
    ushort4 o = { f2bf(v.x), f2bf(v.y), f2bf(v.z), f2bf(v.w) };
    *(ushort4*)(dst + (i - off)) = o;
}

// ---------------- MFMA GEMM core: 128x64 tile, BK=64, double-buffered LDS ----------------
// R19: old schedule was stage -> barrier(vmcnt0 drain, NOTHING overlapping) ->
// read+MFMA -> barrier: full stage latency exposed on the critical path every
// K-step. Now flash_attn's proven pattern: prefetch t+1 into buf^1 while
// computing buf, ONE barrier per iteration — stage latency hides under the
// 8 MFMAs, barrier count halves. LDS 48 KB -> 3 blocks/CU (24 waves, 6/SIMD;
// was 32 waves) — same occupancy-for-overlap trade flash makes.
// Swizzle kept from R17: [.][64] rows, phys colblk = logical ^ (row&7).
__device__ __forceinline__ void gemm_core(
        const unsigned short* __restrict__ A, const unsigned short* __restrict__ W,
        int K, int bm, int bn, unsigned short* As, unsigned short* Bs,
        f32x4 (&acc)[2][2]) {
    const int tid = threadIdx.x;
    const int w = tid >> 6, lane = tid & 63;
    const int quad = lane >> 4, l16 = lane & 15;
    const int wm = (w >> 1) * 32, wn = (w & 1) * 32;

    // staging lane-mapping: row = +(lane>>3), phys colblk = lane&7,
    // logical colblk = phys ^ (row&7)
    const int r8 = lane >> 3, c8 = lane & 7;
    const int scl = (c8 ^ r8) * 8;

    const unsigned short* Ag0 = A + (size_t)(bm +      w*8 + r8) * K + scl;
    const unsigned short* Ag1 = A + (size_t)(bm + 64 + w*8 + r8) * K + scl;
    const unsigned short* Wg0 = W + (size_t)(bn +      w*8 + r8) * K + scl;
    unsigned short* AsD0 = &As[(     w*8) * 64];
    unsigned short* AsD1 = &As[(64 + w*8) * 64];
    unsigned short* BsD  = &Bs[(     w*8) * 64];

    // swizzled fragment-read offsets
    const int fx0 = (quad ^ (l16 & 7)) * 8;
    const int fx1 = ((quad + 4) ^ (l16 & 7)) * 8;

    const int nt = K >> 6;   // 16 K-tiles

    // preload tile 0 into buf 0
    gld_lds16(Ag0, AsD0);
    gld_lds16(Ag1, AsD1);
    gld_lds16(Wg0, BsD);
    __syncthreads();

    for (int t = 0; t < nt; ++t) {
        const int buf = t & 1;
        if (t + 1 < nt) {   // async prefetch of next K-tile into buf^1
            const int k0 = (t + 1) * 64;
            gld_lds16(Ag0 + k0, AsD0 + (buf^1)*8192);
            gld_lds16(Ag1 + k0, AsD1 + (buf^1)*8192);
            gld_lds16(Wg0 + k0, BsD  + (buf^1)*4096);
        }
        const unsigned short* Ab = As + buf*8192;
        const unsigned short* Bb = Bs + buf*4096;
        bf16x8 af0[2], af1[2], bf0[2], bf1[2];
        #pragma unroll
        for (int t2 = 0; t2 < 2; ++t2) {
            af0[t2] = *(const bf16x8*)&Ab[(wm + t2*16 + l16)*64 + fx0];
            af1[t2] = *(const bf16x8*)&Ab[(wm + t2*16 + l16)*64 + fx1];
        }
        #pragma unroll
        for (int c = 0; c < 2; ++c) {
            bf0[c] = *(const bf16x8*)&Bb[(wn + c*16 + l16)*64 + fx0];
            bf1[c] = *(const bf16x8*)&Bb[(wn + c*16 + l16)*64 + fx1];
        }
        #pragma unroll
        for (int t2 = 0; t2 < 2; ++t2)
            #pragma unroll
            for (int c = 0; c < 2; ++c) {
                acc[t2][c] = __builtin_amdgcn_mfma_f32_16x16x32_bf16(af0[t2], bf0[c], acc[t2][c], 0, 0, 0);
                acc[t2][c] = __builtin_amdgcn_mfma_f32_16x16x32_bf16(af1[t2], bf1[c], acc[t2][c], 0, 0, 0);
            }
        __syncthreads();   // drains prefetch + protects buf reuse (one barrier/iter)
    }
}

// ---------------- gemm_proj with fused q-RoPE epilogue (R18, kept) ----------------
__global__ __launch_bounds__(512, 6) void gemm_proj(
        const unsigned short* __restrict__ A, const unsigned short* __restrict__ W,
        unsigned short* __restrict__ qbo, float* __restrict__ okl,
        float* __restrict__ ovl, int K) {
    __shared__ unsigned short As[2*128*64];   // 32 KB
    __shared__ unsigned short Bs[2*64*64];    // 16 KB
    const int bm = blockIdx.y * 128, bn = blockIdx.x * 64;
    f32x4 acc[2][2] = {};
    gemm_core(A, W, K, bm, bn, As, Bs, acc);

    const int tid = threadIdx.x;
    const int w = tid >> 6, lane = tid & 63;
    const int quad = lane >> 4, l16 = lane & 15;
    const int wm = (w >> 1) * 32, wn = (w & 1) * 32;

    if (bn < 1024) {
        // fused RoPE -> qb (bf16)
        const int h = bn >> 6;
        const int p = l16 & 1;
        const float invf0 = __expf(-(float)(l16)      * RFREQ);
        const float invf1 = __expf(-(float)(16 + l16) * RFREQ);
        #pragma unroll
        for (int t = 0; t < 2; ++t)
            #pragma unroll
            for (int r = 0; r < 4; ++r) {
                int row = bm + wm + t*16 + quad*4 + r;   // global token row 0..4095
                int ts  = row & 2047;
                float tf = (float)ts;
                size_t obase = (((size_t)((row >> 11)*16 + h))*TSEQ + ts)*DHEAD;
                #pragma unroll
                for (int c = 0; c < 2; ++c) {
                    float x  = acc[t][c][r];
                    float px = __shfl_xor(x, 1, 64);
                    float sv, cv;
                    __sincosf(tf * (c ? invf1 : invf0), &sv, &cv);
                    float o = (x*cv + (p ? px : -px)*sv) * QSCALE;
                    float po = __shfl_xor(o, 1, 64);
                    if (!p) {
                        unsigned pr = pk2(o, po);
                        *(unsigned*)&qbo[obase + wn + c*16 + l16] = pr;
                    }
                }
            }
    } else {
        float* base; int ldo;
        if (bn < 1536) { base = okl + (bn - 1024); ldo = 512; }
        else           { base = ovl + (bn - 1536); ldo = 512; }
        #pragma unroll
        for (int t = 0; t < 2; ++t)
            #pragma unroll
            for (int c = 0; c < 2; ++c)
                #pragma unroll
                for (int r = 0; r < 4; ++r) {
                    int row = bm + wm + t*16 + quad*4 + r;
                    int col = wn + c*16 + l16;
                    base[(size_t)row * ldo + col] = acc[t][c][r];
                }
    }
}

__global__ __launch_bounds__(512, 6) void gemm_out(
        const unsigned short* __restrict__ A, const unsigned short* __restrict__ W,
        float* __restrict__ O, int N, int K) {
    __shared__ unsigned short As[2*128*64];   // 32 KB
    __shared__ unsigned short Bs[2*64*64];    // 16 KB
    const int bm = blockIdx.y * 128, bn = blockIdx.x * 64;
    f32x4 acc[2][2] = {};
    gemm_core(A, W, K, bm, bn, As, Bs, acc);

    const int tid = threadIdx.x;
    const int w = tid >> 6, lane = tid & 63;
    const int quad = lane >> 4, l16 = lane & 15;
    const int wm = (w >> 1) * 32, wn = (w & 1) * 32;
    #pragma unroll
    for (int t = 0; t < 2; ++t)
        #pragma unroll
        for (int c = 0; c < 2; ++c)
            #pragma unroll
            for (int r = 0; r < 4; ++r) {
                int row = bm + wm + t*16 + quad*4 + r;
                int col = bn + wn + c*16 + l16;
                O[(size_t)row * N + col] = acc[t][c][r];
            }
}

// ---------------- latent up-proj (k,v only) via MFMA + RoPE (R18, kept) ----------------
__global__ __launch_bounds__(256) void latup(
        const float* __restrict__ klat, const float* __restrict__ vlat,
        const unsigned short* __restrict__ wkub, const unsigned short* __restrict__ wvub,
        unsigned short* __restrict__ kb, unsigned short* __restrict__ vt) {
    __shared__ __attribute__((aligned(16))) unsigned short ksh[4][16][72];
    __shared__ __attribute__((aligned(16))) unsigned short vsh[4][64][24];

    const int bh = blockIdx.y, b = bh >> 4, h = bh & 15;
    const int tid = threadIdx.x, w = tid >> 6, lane = tid & 63;
    const int quad = lane >> 4, l16 = lane & 15;
    const int tw = blockIdx.x * 64 + w * 16;   // wave's 16-token base
    const int t  = tw + l16;

    // B-frags (latents): row = token(l16), k = quad*8..+7 — 128 B/token across 4 lanes
    const float* klp = klat + ((size_t)(b*TSEQ + t))*(NHEAD*DLAT) + h*DLAT + quad*8;
    const float* vlp = vlat + ((size_t)(b*TSEQ + t))*(NHEAD*DLAT) + h*DLAT + quad*8;
    float4 kA = *(const float4*)klp, kB = *(const float4*)(klp + 4);
    float4 vA = *(const float4*)vlp, vB = *(const float4*)(vlp + 4);

    // A-frags (Wku/Wvu bf16): row = dim(c*16+l16), k = quad*8..+7
    bf16x8 xk[4], xv[4];
    #pragma unroll
    for (int c = 0; c < 4; ++c) {
        xk[c] = *(const bf16x8*)&wkub[(c*16 + l16)*DLAT + quad*8];
        xv[c] = *(const bf16x8*)&wvub[(c*16 + l16)*DLAT + quad*8];
    }

    union { bf16x8 v; unsigned u[4]; } yk, yv;
    yk.u[0] = pk2(kA.x, kA.y); yk.u[1] = pk2(kA.z, kA.w);
    yk.u[2] = pk2(kB.x, kB.y); yk.u[3] = pk2(kB.z, kB.w);
    yv.u[0] = pk2(vA.x, vA.y); yv.u[1] = pk2(vA.z, vA.w);
    yv.u[2] = pk2(vB.x, vB.y); yv.u[3] = pk2(vB.z, vB.w);

    f32x4 aK[4], aV[4];
    #pragma unroll
    for (int c = 0; c < 4; ++c) {
        f32x4 z = {0.f, 0.f, 0.f, 0.f};
        aK[c] = __builtin_amdgcn_mfma_f32_16x16x32_bf16(xk[c], yk.v, z, 0, 0, 0);
        aV[c] = __builtin_amdgcn_mfma_f32_16x16x32_bf16(xv[c], yv.v, z, 0, 0, 0);
    }

    // angles: dim d = (c&1)*16 + quad*4 + j, freq idx = d&31 — only 8 distinct/thread
    float C0[4], S0[4], C1[4], S1[4];
    const float tf = (float)t;
    #pragma unroll
    for (int j = 0; j < 4; ++j) {
        float f0 = (float)(quad*4 + j);
        __sincosf(tf * __expf(-f0 * RFREQ),          &S0[j], &C0[j]);
        __sincosf(tf * __expf(-(f0 + 16.f) * RFREQ), &S1[j], &C1[j]);
    }

    #pragma unroll
    for (int c = 0; c < 4; ++c) {
        const float* Cs = (c & 1) ? C1 : C0;
        const float* Ss = (c & 1) ? S1 : S0;
        float a0 = aK[c][0], a1 = aK[c][1], a2 = aK[c][2], a3 = aK[c][3];
        unsigned kw0 = pk2(a0*Cs[0] - a1*Ss[0], a1*Cs[1] + a0*Ss[1]);
        unsigned kw1 = pk2(a2*Cs[2] - a3*Ss[2], a3*Cs[3] + a2*Ss[3]);
        *(uint2*)&ksh[w][l16][c*16 + quad*4] = make_uint2(kw0, kw1);

        vsh[w][c*16 + quad*4 + 0][l16] = f2bf(aV[c][0]);
        vsh[w][c*16 + quad*4 + 1][l16] = f2bf(aV[c][1]);
        vsh[w][c*16 + quad*4 + 2][l16] = f2bf(aV[c][2]);
        vsh[w][c*16 + quad*4 + 3][l16] = f2bf(aV[c][3]);
    }

    // wave-local transpose: lockstep + drain LDS writes (no __syncthreads needed)
    __asm__ __volatile__("s_waitcnt lgkmcnt(0)" ::: "memory");

    const int ro = lane >> 2, co = (lane & 3) * 16;
    size_t go = ((size_t)bh*TSEQ + tw + ro)*DHEAD + co;
    int4 k0o = *(const int4*)&ksh[w][ro][co];
    int4 k1o = *(const int4*)&ksh[w][ro][co + 8];
    *(int4*)&kb[go]     = k0o;
    *(int4*)&kb[go + 8] = k1o;

    size_t vo = ((size_t)bh*DHEAD + lane)*TSEQ + tw;
    int4 v0o = *(const int4*)&vsh[w][lane][0];
    int4 v1o = *(const int4*)&vsh[w][lane][8];
    *(int4*)&vt[vo]     = v0o;
    *(int4*)&vt[vo + 8] = v1o;
}

// ---------------- Flash attention: 8-wave blocks, wave-split qt pair (R10, ~48us) ----------------
// Frozen — best-measured structure (Occ 35%, VALU 53% + MFMA 22% = 75%). Do not touch.
__device__ __forceinline__ void online_sm(f32x4 (&s)[8], float& m_run, float& l_run,
                                          f32x4 (&o)[4]) {
    float mx = -1e30f;
    #pragma unroll
    for (int c = 0; c < 8; ++c)
        #pragma unroll
        for (int r = 0; r < 4; ++r) mx = fmaxf(mx, s[c][r]);
    mx = fmaxf(mx, __shfl_xor(mx, 16, 64));
    mx = fmaxf(mx, __shfl_xor(mx, 32, 64));
    if (!__all(mx <= m_run + 8.f)) {   // defer-max: P bounded by 2^8
        float mn = fmaxf(m_run, mx);
        float alpha = __builtin_exp2f(m_run - mn);
        m_run = mn;
        l_run *= alpha;
        #pragma unroll
        for (int c = 0; c < 4; ++c)
            #pragma unroll
            for (int r = 0; r < 4; ++r) o[c][r] *= alpha;
    }
    float ls = 0.f;
    #pragma unroll
    for (int c = 0; c < 8; ++c)
        #pragma unroll
        for (int r = 0; r < 4; ++r) {
            float p = __builtin_exp2f(s[c][r] - m_run);
            s[c][r] = p;
            ls += p;
        }
    ls += __shfl_xor(ls, 16, 64);
    ls += __shfl_xor(ls, 32, 64);
    l_run += ls;
}

__global__ __launch_bounds__(512, 4) void flash_attn(
        const unsigned short* __restrict__ qb, const unsigned short* __restrict__ kb,
        const unsigned short* __restrict__ vtb, unsigned short* __restrict__ yatt) {
    const int bh = blockIdx.x;
    const int b = bh >> 4, h = bh & 15;

    __shared__ unsigned short Ks[2][128][64];    // 32 KB
    __shared__ unsigned short VTs[2][64][128];   // 32 KB

    const int tid  = threadIdx.x;
    const int w    = tid >> 6;          // 0..7
    const int lane = tid & 63;
    const int quad = lane >> 4;
    const int l16  = lane & 15;
    const bool heavy = (w >= 4);
    const int wq = w & 3;               // 16-row group within this wave's half

    const int qtA = blockIdx.y;          // 0..15 (light half)
    const int qtB = 31 - qtA;            // 16..31 (heavy half)
    const int qt  = heavy ? qtB : qtA;
    const int myN = (qt + 2) >> 1;       // KV 128-tiles this wave computes
    const int nB  = (qtB + 2) >> 1;      // loop bound (heavy side)

    const unsigned short* Kbase = kb  + (size_t)bh * TSEQ * DHEAD;
    const unsigned short* Vbase = vtb + (size_t)bh * DHEAD * TSEQ;

    // K DMA: wave w stages tile rows [w*16, w*16+16) — 2 issues x 8 rows
    const int kr8 = lane >> 3, kc8 = lane & 7;
    const int kcl = (kc8 ^ kr8) * 8;            // phys colblk = log ^ (row&7)
    // V DMA: wave w stages dim rows [w*8, w*8+8) — 2 issues x 4 rows
    const int vr4 = lane >> 4, vcp = lane & 15; // phys colblk = log ^ (row&15)

    // swizzled MFMA read offsets
    const int kx0 = (quad ^ (l16 & 7)) * 8;
    const int kx1 = ((quad + 4) ^ (l16 & 7)) * 8;
    const int vq = (quad >> 1), vodd = (quad & 1) * 4;

    const unsigned short* qbase =
        qb + ((size_t)bh*TSEQ + qt*64 + wq*16 + l16) * DHEAD + quad*8;
    bf16x8 q0 = *(const bf16x8*)qbase;
    bf16x8 q1 = *(const bf16x8*)(qbase + 32);

    f32x4 oacc[4] = {};
    float m_run = -1e30f, l_run = 0.f;

    #pragma unroll
    for (int i = 0; i < 2; ++i) {   // preload tile 0 into buf 0
        gld_lds16(Kbase + (size_t)(w*16 + i*8 + kr8)*DHEAD + kcl,
                  &Ks[0][w*16 + i*8][0]);
        int vrow = w*8 + i*4 + vr4;
        int vcl = (vcp ^ (vrow & 15)) * 8;
        gld_lds16(Vbase + (size_t)vrow*TSEQ + vcl, &VTs[0][w*8 + i*4][0]);
    }
    __syncthreads();

    for (int j = 0; j < nB; ++j) {
        const int buf = j & 1;
        if (j + 1 < nB) {   // async DMA prefetch of next tile into buf^1 (ALL waves)
            const int kc = (j + 1) * 128;
            #pragma unroll
            for (int i = 0; i < 2; ++i) {
                gld_lds16(Kbase + (size_t)(kc + w*16 + i*8 + kr8)*DHEAD + kcl,
                          &Ks[buf^1][w*16 + i*8][0]);
                int vrow = w*8 + i*4 + vr4;
                int vcl = (vcp ^ (vrow & 15)) * 8;
                gld_lds16(Vbase + (size_t)vrow*TSEQ + kc + vcl,
                          &VTs[buf^1][w*8 + i*4][0]);
            }
        }

        if (j < myN) {   // wave-uniform guard: light waves idle after their range
            // S^T = K Q^T (8 chunks of 16 K-rows), log2 units
            f32x4 s[8];
            __builtin_amdgcn_s_setprio(1);
            #pragma unroll
            for (int c = 0; c < 8; ++c) {
                bf16x8 ak0 = *(const bf16x8*)&Ks[buf][c*16 + l16][kx0];
                bf16x8 ak1 = *(const bf16x8*)&Ks[buf][c*16 + l16][kx1];
                f32x4 z = {0.f, 0.f, 0.f, 0.f};
                z = __builtin_amdgcn_mfma_f32_16x16x32_bf16(ak0, q0, z, 0, 0, 0);
                z = __builtin_amdgcn_mfma_f32_16x16x32_bf16(ak1, q1, z, 0, 0, 0);
                s[c] = z;
            }
            __builtin_amdgcn_s_setprio(0);

            if (j == myN - 1) {   // causal mask (covers the 128-overhang too)
                #pragma unroll
                for (int c = 0; c < 8; ++c)
                    #pragma unroll
                    for (int r = 0; r < 4; ++r)
                        if (j*128 + c*16 + quad*4 + r > qt*64 + wq*16 + l16)
                            s[c][r] = -1e30f;
            }

            online_sm(s, m_run, l_run, oacc);

            // PV: B-frag = packed P (k=quad*4+e matches 16x16x16), A = swizzled V^T
            __builtin_amdgcn_s_setprio(1);
            #pragma unroll
            for (int c = 0; c < 8; ++c) {
                union { bf16x4 v; unsigned u[2]; } bP;
                bP.u[0] = pack_trunc(s[c][1], s[c][0]);
                bP.u[1] = pack_trunc(s[c][3], s[c][2]);
                const int vcol = ((2*c + vq) ^ l16) * 8 + vodd;
                #pragma unroll
                for (int dc = 0; dc < 4; ++dc) {
                    bf16x4 av = *(const bf16x4*)&VTs[buf][dc*16 + l16][vcol];
                    oacc[dc] = mfma_16x16x16_bf16(av, bP.v, oacc[dc]);
                }
            }
            __builtin_amdgcn_s_setprio(0);
        }

        __syncthreads();   // drains prefetch DMA + protects buf reuse (all waves)
    }

    // epilogue: O^T -> O via per-wave LDS slab (stride 72), coalesced 16B stores
    float invl = 1.0f / l_run;
    unsigned short* Wt = &Ks[0][0][0] + w * (16*72);   // 8 slabs x 2304B < 32KB
    #pragma unroll
    for (int c = 0; c < 4; ++c)
        #pragma unroll
        for (int r = 0; r < 4; ++r)
            Wt[(size_t)l16*72 + c*16 + quad*4 + r] = f2bf(oacc[c][r] * invl);
    __asm__ __volatile__("" ::: "memory");
    #pragma unroll
    for (int p = 0; p < 2; ++p) {
        int row = p*8 + (lane >> 3);
        int d0 = (lane & 7) * 8;
        int4 val = *(const int4*)&Wt[row*72 + d0];
        int tg = qt*64 + wq*16 + row;
        *(int4*)&yatt[((size_t)(b*TSEQ + tg))*CDIM + h*DHEAD + d0] = val;
    }
}

extern "C" void kernel_launch(void* const* d_in, const int* in_sizes, int n_in,
                              void* d_out, int out_size, void* d_ws, size_t ws_size,
                              hipStream_t stream) {
    const float* x   = (const float*)d_in[0];
    const float* Wq  = (const float*)d_in[1];
    const float* Wk  = (const float*)d_in[2];
    const float* Wv  = (const float*)d_in[3];
    const float* Wku = (const float*)d_in[4];
    const float* Wvu = (const float*)d_in[5];
    const float* Wc  = (const float*)d_in[6];

    float* out_y  = (float*)d_out;
    float* out_kl = out_y  + (size_t)MROWS * CDIM;
    float* out_vl = out_kl + (size_t)MROWS * NHEAD*DLAT;

    float* qproj = (float*)d_ws;                                           // 16 MB (yatt alias only)
    unsigned short* xb   = (unsigned short*)(qproj + (size_t)MROWS*CDIM);  // 8 MB
    unsigned short* qb   = xb  + (size_t)MROWS*CDIM;                       // 8 MB
    unsigned short* kb   = qb  + (size_t)MROWS*CDIM;                       // 8 MB
    unsigned short* vt   = kb  + (size_t)MROWS*CDIM;                       // 8 MB
    unsigned short* wall = vt  + (size_t)MROWS*CDIM;                       // [Wq;Wk;Wv;Wc;Wku;Wvu]
    unsigned short* wcb  = wall + (size_t)2048*CDIM;
    unsigned short* wkub = wall + 3145728;
    unsigned short* wvub = wall + 3147776;
    unsigned short* yatt = (unsigned short*)qproj;   // qproj itself is dead (q fused)

    cvt_all<<<7172, 256, 0, stream>>>(x, Wq, Wk, Wv, Wc, Wku, Wvu, xb, wall);

    gemm_proj<<<dim3(2048/64, MROWS/128), 512, 0, stream>>>(
        xb, wall, qb, out_kl, out_vl, CDIM);

    latup<<<dim3(TSEQ/64, NBATCH*NHEAD), 256, 0, stream>>>(
        out_kl, out_vl, wkub, wvub, kb, vt);

    flash_attn<<<dim3(NBATCH*NHEAD, 16), 512, 0, stream>>>(qb, kb, vt, yatt);

    gemm_out<<<dim3(CDIM/64, MROWS/128), 512, 0, stream>>>(yatt, wcb, out_y, CDIM, CDIM);
}